// Round 7
// baseline (403.822 us; speedup 1.0000x reference)
//
#include <hip/hip_runtime.h>
#include <math.h>

#define NB    200
#define DIMH  128
#define ROWS  4
#define TPB   256
#define NITER 22   // 50 in ref; tau err <= 0.411*2^-22 ~ 1e-7 -> p err ~1e-6, far under threshold

__device__ __forceinline__ float pow10_(float x){
    float x2 = x*x; float x4 = x2*x2; float x8 = x4*x4; return x8*x2;
}
__device__ __forceinline__ float rdlane(float v, int l){
    return __builtin_bit_cast(float,
        __builtin_amdgcn_readlane(__builtin_bit_cast(int, v), l));
}
// Wave64 reduce via DPP (row_shr 1/2/4/8 + row_bcast 15/31), uniform result.
__device__ __forceinline__ float wsum_dpp(float v){
#define DPP_ADD(ctrl, rmask)                                                     \
    {                                                                            \
        int t_ = __builtin_amdgcn_update_dpp(0, __builtin_bit_cast(int, v),      \
                                             ctrl, rmask, 0xf, false);           \
        v += __builtin_bit_cast(float, t_);                                      \
    }
    DPP_ADD(0x111, 0xf)
    DPP_ADD(0x112, 0xf)
    DPP_ADD(0x114, 0xf)
    DPP_ADD(0x118, 0xf)
    DPP_ADD(0x142, 0xa)
    DPP_ADD(0x143, 0xc)
#undef DPP_ADD
    return rdlane(v, 63);
}
__device__ __forceinline__ float wmax_dpp(float v){
#define DPP_MAX(ctrl, rmask)                                                     \
    {                                                                            \
        int t_ = __builtin_amdgcn_update_dpp(__builtin_bit_cast(int, v),         \
                                             __builtin_bit_cast(int, v),         \
                                             ctrl, rmask, 0xf, false);           \
        v = fmaxf(v, __builtin_bit_cast(float, t_));                             \
    }
    DPP_MAX(0x111, 0xf)
    DPP_MAX(0x112, 0xf)
    DPP_MAX(0x114, 0xf)
    DPP_MAX(0x118, 0xf)
    DPP_MAX(0x142, 0xa)
    DPP_MAX(0x143, 0xc)
#undef DPP_MAX
    return rdlane(v, 63);
}

// (256,4): only empirically spill-free config (r2/r3/r6: WRITE exactly 25.6MB).
// LDS 32256B <= 32KB -> 5 blocks/CU (r6's 33792B capped us at 4).
__global__ __launch_bounds__(TPB, 4) void la_fused(
    const float* __restrict__ hidden,
    const int*   __restrict__ adj,
    const int*   __restrict__ mask,
    const float* __restrict__ a0, const float* __restrict__ a1,
    const float* __restrict__ a2, const float* __restrict__ a3,
    const float* __restrict__ W,  const float* __restrict__ bias,
    float* __restrict__ out)
{
    __shared__ float ha[ROWS][4][132];   // stride 132: 4-way ksel scatter lands on disjoint banks
    __shared__ float xs[ROWS][208];      // scores, then normalized p (200 + 8 pad)
    __shared__ float cop[ROWS][256];     // gate c-operands: [0:128)=h_i row, [128:256)=o row
    __shared__ float wt[2][16][DIMH];    // W chunk; unpadded (all accesses lane-contiguous)

    const int t    = threadIdx.x;
    const int lane = t & 63;
    const int r    = t >> 6;             // this wave's row
    const int half = lane >> 5;          // 0: j<100 / h-part; 1: j>=100 / o-part
    const int li   = lane & 31;
    const int d4   = 4 * li;             // this lane's 4 dims
    const int bid  = blockIdx.x;
    const int b    = bid / (NB / ROWS);
    const int i0   = (bid % (NB / ROWS)) * ROWS;

    const float* hb = hidden + (size_t)b * NB * DIMH;

    // ---- stage h_i rows (into cop) and ha table ----
    for (int idx = t; idx < ROWS * DIMH; idx += TPB) {
        int rr = idx >> 7, d = idx & 127;
        cop[rr][d] = hb[(i0 + rr) * DIMH + d];
    }
    for (int idx = t; idx < ROWS * 4 * DIMH; idx += TPB) {
        int rr = idx >> 9, k = (idx >> 7) & 3, d = idx & 127;
        float av = (k == 0) ? a0[d] : (k == 1) ? a1[d] : (k == 2) ? a2[d] : a3[d];
        ha[rr][k][d] = hb[(i0 + rr) * DIMH + d] * av;
    }
    __syncthreads();

    // ---- phase S: thread t owns column j=t for all 4 rows ----
    if (t < NB) {
        const int m = mask[b * NB + t];
        int kk[ROWS];
        #pragma unroll
        for (int rr = 0; rr < ROWS; rr++)
            kk[rr] = adj[((size_t)(b * NB + i0 + rr)) * NB + t];
        int ksel[ROWS];
        #pragma unroll
        for (int rr = 0; rr < ROWS; rr++) ksel[rr] = (kk[rr] > 0) ? (kk[rr] - 1) : 0;

        float acc[ROWS] = {0.f, 0.f, 0.f, 0.f};
        const float* hj = hb + t * DIMH;
        #pragma unroll 4
        for (int d = 0; d < DIMH; d += 4) {
            float4 hv = *(const float4*)(hj + d);
            #pragma unroll
            for (int rr = 0; rr < ROWS; rr++) {
                const float4 av4 = *(const float4*)&ha[rr][ksel[rr]][d];
                acc[rr] = fmaf(hv.x, av4.x, acc[rr]);
                acc[rr] = fmaf(hv.y, av4.y, acc[rr]);
                acc[rr] = fmaf(hv.z, av4.z, acc[rr]);
                acc[rr] = fmaf(hv.w, av4.w, acc[rr]);
            }
        }
        #pragma unroll
        for (int rr = 0; rr < ROWS; rr++) {
            float x;
            if (m == 0)           x = -INFINITY;           // mask fill
            else if (kk[rr] == 0) x = 0.0f;                // no edge: sel=0
            else {
                float e = acc[rr];
                e = (e >= 0.0f) ? e : 0.2f * e;            // leaky relu 0.2
                x = e * 0.1f;                              // * (alpha-1)
            }
            xs[rr][t] = x;
        }
    } else if (t < 208) {
        #pragma unroll
        for (int rr = 0; rr < ROWS; rr++) xs[rr][t] = -INFINITY;  // pad cols 200..207
    }
    __syncthreads();

    // ---- entmax bisection: wave r owns row i0+r ----
    float x0 = xs[r][lane];
    float x1 = xs[r][lane + 64];
    float x2 = xs[r][lane + 128];
    float x3 = (lane < 16) ? xs[r][192 + lane] : -INFINITY;   // cols >=208 don't exist

    float mx  = wmax_dpp(fmaxf(fmaxf(x0, x1), fmaxf(x2, x3)));
    float tau = mx - 1.0f;
    float s0  = pow10_(fmaxf(x0 - tau, 0.f)) + pow10_(fmaxf(x1 - tau, 0.f))
              + pow10_(fmaxf(x2 - tau, 0.f)) + pow10_(fmaxf(x3 - tau, 0.f));
    float f_lo = wsum_dpp(s0) - 1.0f;              // captured once (matches ref closure)
    float dm   = (mx - 0.58870401f) - tau;         // tau_hi - tau_lo; (1/200)^0.1

    for (int itn = 0; itn < NITER; ++itn) {
        dm *= 0.5f;
        float tm = tau + dm;
        float s = pow10_(fmaxf(x0 - tm, 0.f)) + pow10_(fmaxf(x1 - tm, 0.f))
                + pow10_(fmaxf(x2 - tm, 0.f)) + pow10_(fmaxf(x3 - tm, 0.f));
        float fm = wsum_dpp(s) - 1.0f;
        if (fm * f_lo >= 0.0f) tau = tm;
    }
    float p0 = pow10_(fmaxf(x0 - tau, 0.f));
    float p1 = pow10_(fmaxf(x1 - tau, 0.f));
    float p2 = pow10_(fmaxf(x2 - tau, 0.f));
    float p3 = pow10_(fmaxf(x3 - tau, 0.f));
    float sinv = 1.0f / wsum_dpp(p0 + p1 + p2 + p3);   // ensure_sum_one
    xs[r][lane]       = p0 * sinv;                     // wave-local write-back
    xs[r][lane + 64]  = p1 * sinv;
    xs[r][lane + 128] = p2 * sinv;
    if (lane < 16) xs[r][192 + lane] = p3 * sinv;      // lanes 8..15 store 0 (never read)

    // ---- PV, half-split float4: half h covers j in [100h,100h+100), dims d4..d4+3 ----
    float4 o = make_float4(0.f, 0.f, 0.f, 0.f);
    {
        const float* hbase = hb + half * 100 * DIMH + d4;
        const float* xrow  = &xs[r][half * 100];
        #pragma unroll 4
        for (int jj = 0; jj < 100; ++jj) {
            float pj = xrow[jj];                       // uniform-addr LDS broadcast
            float4 hv = *(const float4*)(hbase + jj * DIMH);
            o.x = fmaf(pj, hv.x, o.x);
            o.y = fmaf(pj, hv.y, o.y);
            o.z = fmaf(pj, hv.z, o.z);
            o.w = fmaf(pj, hv.w, o.w);
        }
    }
    o.x += __shfl_xor(o.x, 32);                        // combine the two j-halves
    o.y += __shfl_xor(o.y, 32);
    o.z += __shfl_xor(o.z, 32);
    o.w += __shfl_xor(o.w, 32);
    if (half == 0) *(float4*)&cop[r][DIMH + d4] = o;   // wave-local publish for gate

    // ---- gate with T14 prefetch: g[d] = sum_e c[e] W[e][d] ----
    // half 0: c = h_i, W rows 0..127; half 1: c = o, W rows 128..255.
    float4 g = make_float4(0.f, 0.f, 0.f, 0.f);
    const float* cbase = &cop[r][half * DIMH];

    // chunk c = 16 W rows per part; thread t stages 4 float4s (fidx = q*256+t)
    float4 pre0, pre1, pre2, pre3;
#define WSRC(q, c) (*(const float4*)(W + (size_t)((((q * TPB + t) >> 9) * DIMH          \
                        + (c) * 16 + (((q * TPB + t) >> 5) & 15)) * DIMH                 \
                        + ((q * TPB + t) & 31) * 4)))
#define WDST(q) (((float4*)&wt[0][0][0])[q * TPB + t])
    pre0 = WSRC(0, 0); pre1 = WSRC(1, 0); pre2 = WSRC(2, 0); pre3 = WSRC(3, 0);

    for (int c = 0; c < 8; ++c) {
        __syncthreads();                               // all waves done reading wt
        WDST(0) = pre0; WDST(1) = pre1; WDST(2) = pre2; WDST(3) = pre3;
        if (c < 7) {                                   // issue next chunk early (T14)
            pre0 = WSRC(0, c + 1); pre1 = WSRC(1, c + 1);
            pre2 = WSRC(2, c + 1); pre3 = WSRC(3, c + 1);
        }
        __syncthreads();                               // wt chunk c visible
        #pragma unroll
        for (int e = 0; e < 16; ++e) {
            float cv = cbase[c * 16 + e];              // uniform-addr LDS broadcast
            float4 wv = *(const float4*)&wt[half][e][d4];
            g.x = fmaf(cv, wv.x, g.x);
            g.y = fmaf(cv, wv.y, g.y);
            g.z = fmaf(cv, wv.z, g.z);
            g.w = fmaf(cv, wv.w, g.w);
        }
    }
#undef WSRC
#undef WDST
    g.x += __shfl_xor(g.x, 32);                        // combine h-part + o-part
    g.y += __shfl_xor(g.y, 32);
    g.z += __shfl_xor(g.z, 32);
    g.w += __shfl_xor(g.w, 32);
    float4 bv = *(const float4*)(bias + d4);           // bias once, post-combine
    g.x += bv.x; g.y += bv.y; g.z += bv.z; g.w += bv.w;

    float4 sg;
    sg.x = 1.0f / (1.0f + __expf(-g.x));
    sg.y = 1.0f / (1.0f + __expf(-g.y));
    sg.z = 1.0f / (1.0f + __expf(-g.z));
    sg.w = 1.0f / (1.0f + __expf(-g.w));

    if (half == 0) {
        float4 hf = *(const float4*)&cop[r][d4];       // h_i dims d4..d4+3
        const size_t gi = (size_t)(b * NB + i0 + r) * DIMH;
        float4 res;
        res.x = sg.x * o.x + (1.0f - sg.x) * hf.x;
        res.y = sg.y * o.y + (1.0f - sg.y) * hf.y;
        res.z = sg.z * o.z + (1.0f - sg.z) * hf.z;
        res.w = sg.w * o.w + (1.0f - sg.w) * hf.w;
        *(float4*)(out + gi + d4) = res;
    }
}

extern "C" void kernel_launch(void* const* d_in, const int* in_sizes, int n_in,
                              void* d_out, int out_size, void* d_ws, size_t ws_size,
                              hipStream_t stream)
{
    const float* hidden = (const float*)d_in[0];
    const int*   adj    = (const int*)d_in[1];
    const int*   mask   = (const int*)d_in[2];
    const float* a0     = (const float*)d_in[3];
    const float* a1     = (const float*)d_in[4];
    const float* a2     = (const float*)d_in[5];
    const float* a3     = (const float*)d_in[6];
    const float* W      = (const float*)d_in[7];
    const float* bias   = (const float*)d_in[8];
    float* out = (float*)d_out;

    const int B = in_sizes[0] / (NB * DIMH);   // 256
    dim3 grid(B * (NB / ROWS));
    la_fused<<<grid, TPB, 0, stream>>>(hidden, adj, mask, a0, a1, a2, a3, W, bias, out);
}

// Round 8
// 376.768 us; speedup vs baseline: 1.0718x; 1.0718x over previous
//
#include <hip/hip_runtime.h>
#include <math.h>

#define NB    200
#define DIMH  128
#define ROWS  4
#define TPB   256
#define NITER 22   // 50 in ref; tau err <= 0.411*2^-22 ~ 1e-7 -> p err ~1e-6, far under threshold
#define NJT   13   // j-tiles of 16 covering 208 (200 + pad)

typedef __attribute__((ext_vector_type(8))) short  short8v;  // 8 bf16 = 4 VGPRs (MFMA A/B frag)
typedef __attribute__((ext_vector_type(4))) float  f32x4;    // MFMA C/D frag
typedef __attribute__((ext_vector_type(4))) unsigned u32x4;

// Truncation hi/lo split: hi = top-16-bits of f32 (exact), lo = x - hi (exact f32),
// packed as bf16x2 per u32 (low half = first/even element).
__device__ __forceinline__ unsigned pack_hi2(float a, float b){
    return (__builtin_bit_cast(unsigned, a) >> 16) |
           (__builtin_bit_cast(unsigned, b) & 0xFFFF0000u);
}
__device__ __forceinline__ float hi_of(float x){
    return __builtin_bit_cast(float, __builtin_bit_cast(unsigned, x) & 0xFFFF0000u);
}
__device__ __forceinline__ float rdlane(float v, int l){
    return __builtin_bit_cast(float,
        __builtin_amdgcn_readlane(__builtin_bit_cast(int, v), l));
}
// Wave64 reduce via DPP (row_shr 1/2/4/8 + row_bcast 15/31), uniform result.
__device__ __forceinline__ float wsum_dpp(float v){
#define DPP_ADD(ctrl, rmask)                                                     \
    {                                                                            \
        int t_ = __builtin_amdgcn_update_dpp(0, __builtin_bit_cast(int, v),      \
                                             ctrl, rmask, 0xf, false);           \
        v += __builtin_bit_cast(float, t_);                                      \
    }
    DPP_ADD(0x111, 0xf)
    DPP_ADD(0x112, 0xf)
    DPP_ADD(0x114, 0xf)
    DPP_ADD(0x118, 0xf)
    DPP_ADD(0x142, 0xa)
    DPP_ADD(0x143, 0xc)
#undef DPP_ADD
    return rdlane(v, 63);
}
__device__ __forceinline__ float wmax_dpp(float v){
#define DPP_MAX(ctrl, rmask)                                                     \
    {                                                                            \
        int t_ = __builtin_amdgcn_update_dpp(__builtin_bit_cast(int, v),         \
                                             __builtin_bit_cast(int, v),         \
                                             ctrl, rmask, 0xf, false);           \
        v = fmaxf(v, __builtin_bit_cast(float, t_));                             \
    }
    DPP_MAX(0x111, 0xf)
    DPP_MAX(0x112, 0xf)
    DPP_MAX(0x114, 0xf)
    DPP_MAX(0x118, 0xf)
    DPP_MAX(0x142, 0xa)
    DPP_MAX(0x143, 0xc)
#undef DPP_MAX
    return rdlane(v, 63);
}

// (256,4): only empirically spill-free config (r2/r3/r6/r7: WRITE exactly 25.6MB).
__global__ __launch_bounds__(TPB, 4) void la_fused(
    const float* __restrict__ hidden,
    const int*   __restrict__ adj,
    const int*   __restrict__ mask,
    const float* __restrict__ a0, const float* __restrict__ a1,
    const float* __restrict__ a2, const float* __restrict__ a3,
    const float* __restrict__ W,  const float* __restrict__ bias,
    float* __restrict__ out)
{
    __shared__ unsigned hab[2][16][68];  // ha bf16x2 [hi/lo][rk][d2]; stride 68 u32 = 16B-aligned rows
    __shared__ float xs[ROWS][208];      // scores, then normalized p (200 + 8 pad)
    __shared__ float cop[ROWS][256];     // gate c-operands: [0:128)=h_i row, [128:256)=o row
    __shared__ float wt[2][16][DIMH];    // W chunk (gate)

    const int t    = threadIdx.x;
    const int lane = t & 63;
    const int r    = t >> 6;             // wave id == row owned in entmax/PV/gate
    const int half = lane >> 5;          // PV/gate half-split
    const int li   = lane & 31;
    const int d4   = 4 * li;
    const int bid  = blockIdx.x;
    const int b    = bid / (NB / ROWS);
    const int i0   = (bid % (NB / ROWS)) * ROWS;

    const float* hb = hidden + (size_t)b * NB * DIMH;

    // ---- stage h_i rows (cop) and the bf16 hi/lo ha table ----
    for (int idx = t; idx < ROWS * DIMH; idx += TPB) {
        int rr = idx >> 7, d = idx & 127;
        cop[rr][d] = hb[(i0 + rr) * DIMH + d];
    }
    for (int s = t; s < 16 * 64; s += TPB) {           // 16 rk-rows x 64 u32 (=128 bf16 d's)
        int rk = s >> 6, d2 = s & 63;
        int rr = rk >> 2, k = rk & 3;
        int d  = d2 * 2;
        const float* ap = (k == 0) ? a0 : (k == 1) ? a1 : (k == 2) ? a2 : a3;
        float h0 = hb[(i0 + rr) * DIMH + d];
        float h1 = hb[(i0 + rr) * DIMH + d + 1];
        float p0 = h0 * ap[d];
        float p1 = h1 * ap[d + 1];
        hab[0][rk][d2] = pack_hi2(p0, p1);
        hab[1][rk][d2] = pack_hi2(p0 - hi_of(p0), p1 - hi_of(p1));
    }
    __syncthreads();

    // ---- A-fragments: lane l holds HA[l&15][(l>>4)*8 + q], q=0..7, per K-step ----
    short8v Ahi[4], Alo[4];
    {
        const int arow = lane & 15;
        const int au   = (lane >> 4) * 4;              // u32 offset within row
        #pragma unroll
        for (int ks = 0; ks < 4; ++ks) {
            u32x4 h4 = *(const u32x4*)&hab[0][arow][ks * 16 + au];
            u32x4 l4 = *(const u32x4*)&hab[1][arow][ks * 16 + au];
            Ahi[ks] = __builtin_bit_cast(short8v, h4);
            Alo[ks] = __builtin_bit_cast(short8v, l4);
        }
    }

    // ---- score via MFMA: E[rk][j] = sum_d HA[rk][d] * H[j][d]; wave w does jt = w,w+4,... ----
    const int jcol = lane & 15;
    const int kgrp = lane >> 4;
    for (int jt = r; jt < NJT; jt += 4) {
        const int jrow = jt * 16 + jcol;
        const int jl   = (jrow < NB) ? jrow : (NB - 1);          // clamp (pad lanes discarded)
        const float* hj = hb + (size_t)jl * DIMH + kgrp * 8;
        float4 rw[8];
        #pragma unroll
        for (int ks = 0; ks < 4; ++ks) {
            rw[2 * ks]     = *(const float4*)(hj + ks * 32);
            rw[2 * ks + 1] = *(const float4*)(hj + ks * 32 + 4);
        }
        f32x4 acc = {0.f, 0.f, 0.f, 0.f};
        #pragma unroll
        for (int ks = 0; ks < 4; ++ks) {
            float v0 = rw[2*ks].x, v1 = rw[2*ks].y, v2 = rw[2*ks].z, v3 = rw[2*ks].w;
            float v4 = rw[2*ks+1].x, v5 = rw[2*ks+1].y, v6 = rw[2*ks+1].z, v7 = rw[2*ks+1].w;
            u32x4 bh = { pack_hi2(v0, v1), pack_hi2(v2, v3),
                         pack_hi2(v4, v5), pack_hi2(v6, v7) };
            u32x4 bl = { pack_hi2(v0 - hi_of(v0), v1 - hi_of(v1)),
                         pack_hi2(v2 - hi_of(v2), v3 - hi_of(v3)),
                         pack_hi2(v4 - hi_of(v4), v5 - hi_of(v5)),
                         pack_hi2(v6 - hi_of(v6), v7 - hi_of(v7)) };
            short8v Bhi = __builtin_bit_cast(short8v, bh);
            short8v Blo = __builtin_bit_cast(short8v, bl);
            acc = __builtin_amdgcn_mfma_f32_16x16x32_bf16(Ahi[ks], Bhi, acc, 0, 0, 0);
            acc = __builtin_amdgcn_mfma_f32_16x16x32_bf16(Alo[ks], Bhi, acc, 0, 0, 0);
            acc = __builtin_amdgcn_mfma_f32_16x16x32_bf16(Ahi[ks], Blo, acc, 0, 0, 0);
        }
        // lane-local edge-type select: reg i = E[rk=4*kgrp+i] = k-type i for row kgrp
        int kk = adj[(size_t)(b * NB + i0 + kgrp) * NB + jl];
        int mm = mask[b * NB + jl];
        float ev = (kk == 1) ? acc[0] : (kk == 2) ? acc[1] :
                   (kk == 3) ? acc[2] : (kk == 4) ? acc[3] : 0.0f;
        ev = (ev >= 0.0f) ? ev : 0.2f * ev;            // leaky relu 0.2 (0 stays 0)
        float x = ev * 0.1f;                           // * (alpha-1)
        if (mm == 0)     x = -INFINITY;                // mask fill
        if (jrow >= NB)  x = -INFINITY;                // pad cols 200..207
        xs[kgrp][jrow] = x;
    }
    __syncthreads();                                   // all waves wrote all rows of xs

    // ---- entmax bisection: wave r owns row i0+r ----
    float x0 = xs[r][lane];
    float x1 = xs[r][lane + 64];
    float x2 = xs[r][lane + 128];
    float x3 = (lane < 16) ? xs[r][192 + lane] : -INFINITY;

    float mx  = wmax_dpp(fmaxf(fmaxf(x0, x1), fmaxf(x2, x3)));
    float tau = mx - 1.0f;
    #define P10(v, tt) ({ float z_ = fmaxf((v) - (tt), 0.f); float z2 = z_*z_; float z4 = z2*z2; float z8 = z4*z4; z8*z2; })
    float s0 = P10(x0, tau) + P10(x1, tau) + P10(x2, tau) + P10(x3, tau);
    float f_lo = wsum_dpp(s0) - 1.0f;              // captured once (matches ref closure)
    float dm   = (mx - 0.58870401f) - tau;         // tau_hi - tau_lo; (1/200)^0.1

    for (int itn = 0; itn < NITER; ++itn) {
        dm *= 0.5f;
        float tm = tau + dm;
        float s = P10(x0, tm) + P10(x1, tm) + P10(x2, tm) + P10(x3, tm);
        float fm = wsum_dpp(s) - 1.0f;
        if (fm * f_lo >= 0.0f) tau = tm;
    }
    float p0 = P10(x0, tau);
    float p1 = P10(x1, tau);
    float p2 = P10(x2, tau);
    float p3 = P10(x3, tau);
    #undef P10
    float sinv = 1.0f / wsum_dpp(p0 + p1 + p2 + p3);   // ensure_sum_one
    xs[r][lane]       = p0 * sinv;                     // wave-local write-back
    xs[r][lane + 64]  = p1 * sinv;
    xs[r][lane + 128] = p2 * sinv;
    if (lane < 16) xs[r][192 + lane] = p3 * sinv;

    // ---- PV, half-split float4: half h covers j in [100h,100h+100), dims d4..d4+3 ----
    float4 o = make_float4(0.f, 0.f, 0.f, 0.f);
    {
        const float* hbase = hb + half * 100 * DIMH + d4;
        const float* xrow  = &xs[r][half * 100];
        #pragma unroll 4
        for (int jj = 0; jj < 100; ++jj) {
            float pj = xrow[jj];                       // uniform-addr LDS broadcast
            float4 hv = *(const float4*)(hbase + jj * DIMH);
            o.x = fmaf(pj, hv.x, o.x);
            o.y = fmaf(pj, hv.y, o.y);
            o.z = fmaf(pj, hv.z, o.z);
            o.w = fmaf(pj, hv.w, o.w);
        }
    }
    o.x += __shfl_xor(o.x, 32);                        // combine the two j-halves
    o.y += __shfl_xor(o.y, 32);
    o.z += __shfl_xor(o.z, 32);
    o.w += __shfl_xor(o.w, 32);
    if (half == 0) *(float4*)&cop[r][DIMH + d4] = o;   // wave-local publish for gate

    // ---- gate with prefetch: g[d] = sum_e c[e] W[e][d] ----
    float4 g = make_float4(0.f, 0.f, 0.f, 0.f);
    const float* cbase = &cop[r][half * DIMH];

    float4 pre0, pre1, pre2, pre3;
#define WSRC(q, c) (*(const float4*)(W + (size_t)((((q * TPB + t) >> 9) * DIMH          \
                        + (c) * 16 + (((q * TPB + t) >> 5) & 15)) * DIMH                 \
                        + ((q * TPB + t) & 31) * 4)))
#define WDST(q) (((float4*)&wt[0][0][0])[q * TPB + t])
    pre0 = WSRC(0, 0); pre1 = WSRC(1, 0); pre2 = WSRC(2, 0); pre3 = WSRC(3, 0);

    for (int c = 0; c < 8; ++c) {
        __syncthreads();                               // all waves done reading wt
        WDST(0) = pre0; WDST(1) = pre1; WDST(2) = pre2; WDST(3) = pre3;
        if (c < 7) {                                   // issue next chunk early (T14)
            pre0 = WSRC(0, c + 1); pre1 = WSRC(1, c + 1);
            pre2 = WSRC(2, c + 1); pre3 = WSRC(3, c + 1);
        }
        __syncthreads();                               // wt chunk c visible
        #pragma unroll
        for (int e = 0; e < 16; ++e) {
            float cv = cbase[c * 16 + e];              // uniform-addr LDS broadcast
            float4 wv = *(const float4*)&wt[half][e][d4];
            g.x = fmaf(cv, wv.x, g.x);
            g.y = fmaf(cv, wv.y, g.y);
            g.z = fmaf(cv, wv.z, g.z);
            g.w = fmaf(cv, wv.w, g.w);
        }
    }
#undef WSRC
#undef WDST
    g.x += __shfl_xor(g.x, 32);                        // combine h-part + o-part
    g.y += __shfl_xor(g.y, 32);
    g.z += __shfl_xor(g.z, 32);
    g.w += __shfl_xor(g.w, 32);
    float4 bv = *(const float4*)(bias + d4);           // bias once, post-combine
    g.x += bv.x; g.y += bv.y; g.z += bv.z; g.w += bv.w;

    float4 sg;
    sg.x = 1.0f / (1.0f + __expf(-g.x));
    sg.y = 1.0f / (1.0f + __expf(-g.y));
    sg.z = 1.0f / (1.0f + __expf(-g.z));
    sg.w = 1.0f / (1.0f + __expf(-g.w));

    if (half == 0) {
        float4 hf = *(const float4*)&cop[r][d4];       // h_i dims d4..d4+3
        const size_t gi = (size_t)(b * NB + i0 + r) * DIMH;
        float4 res;
        res.x = sg.x * o.x + (1.0f - sg.x) * hf.x;
        res.y = sg.y * o.y + (1.0f - sg.y) * hf.y;
        res.z = sg.z * o.z + (1.0f - sg.z) * hf.z;
        res.w = sg.w * o.w + (1.0f - sg.w) * hf.w;
        *(float4*)(out + gi + d4) = res;
    }
}

extern "C" void kernel_launch(void* const* d_in, const int* in_sizes, int n_in,
                              void* d_out, int out_size, void* d_ws, size_t ws_size,
                              hipStream_t stream)
{
    const float* hidden = (const float*)d_in[0];
    const int*   adj    = (const int*)d_in[1];
    const int*   mask   = (const int*)d_in[2];
    const float* a0     = (const float*)d_in[3];
    const float* a1     = (const float*)d_in[4];
    const float* a2     = (const float*)d_in[5];
    const float* a3     = (const float*)d_in[6];
    const float* W      = (const float*)d_in[7];
    const float* bias   = (const float*)d_in[8];
    float* out = (float*)d_out;

    const int B = in_sizes[0] / (NB * DIMH);   // 256
    dim3 grid(B * (NB / ROWS));
    la_fused<<<grid, TPB, 0, stream>>>(hidden, adj, mask, a0, a1, a2, a3, W, bias, out);
}

// Round 9
// 360.813 us; speedup vs baseline: 1.1192x; 1.0442x over previous
//
#include <hip/hip_runtime.h>
#include <math.h>

#define NB    200
#define DIMH  128
#define ROWS  4
#define TPB   256
#define NITER 22   // 50 in ref; tau err <= 0.411*2^-22 ~ 1e-7 -> p err ~1e-6, far under threshold
#define NJT   13   // j-tiles of 16 covering 208 (200 + pad)

typedef __attribute__((ext_vector_type(8))) short  short8v;  // 8 bf16 = 4 VGPRs (MFMA A/B frag)
typedef __attribute__((ext_vector_type(4))) float  f32x4;    // MFMA C/D frag
typedef __attribute__((ext_vector_type(4))) unsigned u32x4;

// Truncation hi/lo split: hi = top-16-bits of f32 (exact), lo = x - hi (exact f32).
__device__ __forceinline__ unsigned pack_hi2(float a, float b){
    return (__builtin_bit_cast(unsigned, a) >> 16) |
           (__builtin_bit_cast(unsigned, b) & 0xFFFF0000u);
}
__device__ __forceinline__ float hi_of(float x){
    return __builtin_bit_cast(float, __builtin_bit_cast(unsigned, x) & 0xFFFF0000u);
}
__device__ __forceinline__ float rdlane(float v, int l){
    return __builtin_bit_cast(float,
        __builtin_amdgcn_readlane(__builtin_bit_cast(int, v), l));
}
// Wave64 reduce via DPP (row_shr 1/2/4/8 + row_bcast 15/31), uniform result.
__device__ __forceinline__ float wsum_dpp(float v){
#define DPP_ADD(ctrl, rmask)                                                     \
    {                                                                            \
        int t_ = __builtin_amdgcn_update_dpp(0, __builtin_bit_cast(int, v),      \
                                             ctrl, rmask, 0xf, false);           \
        v += __builtin_bit_cast(float, t_);                                      \
    }
    DPP_ADD(0x111, 0xf)
    DPP_ADD(0x112, 0xf)
    DPP_ADD(0x114, 0xf)
    DPP_ADD(0x118, 0xf)
    DPP_ADD(0x142, 0xa)
    DPP_ADD(0x143, 0xc)
#undef DPP_ADD
    return rdlane(v, 63);
}
__device__ __forceinline__ float wmax_dpp(float v){
#define DPP_MAX(ctrl, rmask)                                                     \
    {                                                                            \
        int t_ = __builtin_amdgcn_update_dpp(__builtin_bit_cast(int, v),         \
                                             __builtin_bit_cast(int, v),         \
                                             ctrl, rmask, 0xf, false);           \
        v = fmaxf(v, __builtin_bit_cast(float, t_));                             \
    }
    DPP_MAX(0x111, 0xf)
    DPP_MAX(0x112, 0xf)
    DPP_MAX(0x114, 0xf)
    DPP_MAX(0x118, 0xf)
    DPP_MAX(0x142, 0xa)
    DPP_MAX(0x143, 0xc)
#undef DPP_MAX
    return rdlane(v, 63);
}

// (256,4): only empirically spill-free config. WRITE_SIZE must read exactly 25600KB.
__global__ __launch_bounds__(TPB, 4) void la_fused(
    const float* __restrict__ hidden,
    const int*   __restrict__ adj,
    const int*   __restrict__ mask,
    const float* __restrict__ a0, const float* __restrict__ a1,
    const float* __restrict__ a2, const float* __restrict__ a3,
    const float* __restrict__ W,  const float* __restrict__ bias,
    float* __restrict__ out)
{
    __shared__ unsigned hab[2][16][68];  // ha bf16x2 [hi/lo][rk][d2], 16B-aligned rows
    __shared__ float xs[ROWS][208];      // scores, then normalized p (200 + 8 pad)
    __shared__ float cop[ROWS][256];     // [0:128)=h_i row, [128:256)=o row
    __shared__ float pp[ROWS][ROWS][DIMH]; // [wave][row] partial sums (PV, then gate)

    const int t    = threadIdx.x;
    const int lane = t & 63;
    const int r    = t >> 6;             // wave id
    const int d2   = 2 * lane;           // this lane's 2 dims in PV/gate/out
    const int bid  = blockIdx.x;
    const int b    = bid / (NB / ROWS);
    const int i0   = (bid % (NB / ROWS)) * ROWS;

    const float* hb = hidden + (size_t)b * NB * DIMH;

    // ---- stage h_i rows (cop) and the bf16 hi/lo ha table ----
    for (int idx = t; idx < ROWS * DIMH; idx += TPB) {
        int rr = idx >> 7, d = idx & 127;
        cop[rr][d] = hb[(i0 + rr) * DIMH + d];
    }
    for (int s = t; s < 16 * 64; s += TPB) {           // 16 rk-rows x 64 u32
        int rk = s >> 6, dd = s & 63;
        int rr = rk >> 2, k = rk & 3;
        int d  = dd * 2;
        const float* ap = (k == 0) ? a0 : (k == 1) ? a1 : (k == 2) ? a2 : a3;
        float h0 = hb[(i0 + rr) * DIMH + d];
        float h1 = hb[(i0 + rr) * DIMH + d + 1];
        float q0 = h0 * ap[d];
        float q1 = h1 * ap[d + 1];
        hab[0][rk][dd] = pack_hi2(q0, q1);
        hab[1][rk][dd] = pack_hi2(q0 - hi_of(q0), q1 - hi_of(q1));
    }
    __syncthreads();                                   // A

    // ---- A-fragments: lane l holds HA[l&15][(l>>4)*8 + q] per K-step ----
    short8v Ahi[4], Alo[4];
    {
        const int arow = lane & 15;
        const int au   = (lane >> 4) * 4;
        #pragma unroll
        for (int ks = 0; ks < 4; ++ks) {
            Ahi[ks] = __builtin_bit_cast(short8v, *(const u32x4*)&hab[0][arow][ks * 16 + au]);
            Alo[ks] = __builtin_bit_cast(short8v, *(const u32x4*)&hab[1][arow][ks * 16 + au]);
        }
    }

    // ---- score via MFMA: E[rk][j]; wave w does j-tiles w, w+4, ... ----
    const int jcol = lane & 15;
    const int kgrp = lane >> 4;
    for (int jt = r; jt < NJT; jt += 4) {
        const int jrow = jt * 16 + jcol;
        const int jl   = (jrow < NB) ? jrow : (NB - 1);
        const float* hj = hb + (size_t)jl * DIMH + kgrp * 8;
        f32x4 acc = {0.f, 0.f, 0.f, 0.f};
        #pragma unroll
        for (int ks = 0; ks < 4; ++ks) {               // convert per-ks (low reg pressure)
            float4 ra = *(const float4*)(hj + ks * 32);
            float4 rb = *(const float4*)(hj + ks * 32 + 4);
            u32x4 bh = { pack_hi2(ra.x, ra.y), pack_hi2(ra.z, ra.w),
                         pack_hi2(rb.x, rb.y), pack_hi2(rb.z, rb.w) };
            u32x4 bl = { pack_hi2(ra.x - hi_of(ra.x), ra.y - hi_of(ra.y)),
                         pack_hi2(ra.z - hi_of(ra.z), ra.w - hi_of(ra.w)),
                         pack_hi2(rb.x - hi_of(rb.x), rb.y - hi_of(rb.y)),
                         pack_hi2(rb.z - hi_of(rb.z), rb.w - hi_of(rb.w)) };
            short8v Bhi = __builtin_bit_cast(short8v, bh);
            short8v Blo = __builtin_bit_cast(short8v, bl);
            acc = __builtin_amdgcn_mfma_f32_16x16x32_bf16(Ahi[ks], Bhi, acc, 0, 0, 0);
            acc = __builtin_amdgcn_mfma_f32_16x16x32_bf16(Alo[ks], Bhi, acc, 0, 0, 0);
            acc = __builtin_amdgcn_mfma_f32_16x16x32_bf16(Ahi[ks], Blo, acc, 0, 0, 0);
        }
        int kk = adj[(size_t)(b * NB + i0 + kgrp) * NB + jl];
        int mm = mask[b * NB + jl];
        float ev = (kk == 1) ? acc[0] : (kk == 2) ? acc[1] :
                   (kk == 3) ? acc[2] : (kk == 4) ? acc[3] : 0.0f;
        ev = (ev >= 0.0f) ? ev : 0.2f * ev;            // leaky relu 0.2
        float x = ev * 0.1f;                           // * (alpha-1)
        if (mm == 0)     x = -INFINITY;
        if (jrow >= NB)  x = -INFINITY;                // pad cols 200..207
        xs[kgrp][jrow] = x;
    }
    __syncthreads();                                   // B

    // ---- entmax bisection: wave r owns row i0+r ----
    float x0 = xs[r][lane];
    float x1 = xs[r][lane + 64];
    float x2 = xs[r][lane + 128];
    float x3 = (lane < 16) ? xs[r][192 + lane] : -INFINITY;

    float mx  = wmax_dpp(fmaxf(fmaxf(x0, x1), fmaxf(x2, x3)));
    float tau = mx - 1.0f;
    #define P10(v, tt) ({ float z_ = fmaxf((v) - (tt), 0.f); float z2 = z_*z_; float z4 = z2*z2; float z8 = z4*z4; z8*z2; })
    float s0 = P10(x0, tau) + P10(x1, tau) + P10(x2, tau) + P10(x3, tau);
    float f_lo = wsum_dpp(s0) - 1.0f;              // captured once (matches ref closure)
    float dm   = (mx - 0.58870401f) - tau;         // (1/200)^0.1

    for (int itn = 0; itn < NITER; ++itn) {
        dm *= 0.5f;
        float tm = tau + dm;
        float s = P10(x0, tm) + P10(x1, tm) + P10(x2, tm) + P10(x3, tm);
        float fm = wsum_dpp(s) - 1.0f;
        if (fm * f_lo >= 0.0f) tau = tm;
    }
    float p0 = P10(x0, tau);
    float p1 = P10(x1, tau);
    float p2 = P10(x2, tau);
    float p3 = P10(x3, tau);
    #undef P10
    float sinv = 1.0f / wsum_dpp(p0 + p1 + p2 + p3);   // ensure_sum_one
    xs[r][lane]       = p0 * sinv;
    xs[r][lane + 64]  = p1 * sinv;
    xs[r][lane + 128] = p2 * sinv;
    if (lane < 16) xs[r][192 + lane] = p3 * sinv;
    __syncthreads();                                   // C: PV reads all rows' p

    // ---- PV split-K: wave w owns j in [50w, 50w+50), partials for ALL 4 rows ----
    const int J0 = r * 50;
    float pj0 = (lane < 50) ? xs[0][J0 + lane] : 0.f;  // lane l holds p[row][J0+l]
    float pj1 = (lane < 50) ? xs[1][J0 + lane] : 0.f;
    float pj2 = (lane < 50) ? xs[2][J0 + lane] : 0.f;
    float pj3 = (lane < 50) ? xs[3][J0 + lane] : 0.f;
    float2 ov0 = {0.f,0.f}, ov1 = {0.f,0.f}, ov2 = {0.f,0.f}, ov3 = {0.f,0.f};
    {
        const float* hjb = hb + (size_t)J0 * DIMH + d2;
        #pragma unroll 5
        for (int jj = 0; jj < 50; ++jj) {
            float2 hv = *(const float2*)(hjb + jj * DIMH);
            float c0 = rdlane(pj0, jj), c1 = rdlane(pj1, jj);
            float c2 = rdlane(pj2, jj), c3 = rdlane(pj3, jj);
            ov0.x = fmaf(c0, hv.x, ov0.x); ov0.y = fmaf(c0, hv.y, ov0.y);
            ov1.x = fmaf(c1, hv.x, ov1.x); ov1.y = fmaf(c1, hv.y, ov1.y);
            ov2.x = fmaf(c2, hv.x, ov2.x); ov2.y = fmaf(c2, hv.y, ov2.y);
            ov3.x = fmaf(c3, hv.x, ov3.x); ov3.y = fmaf(c3, hv.y, ov3.y);
        }
    }
    *(float2*)&pp[r][0][d2] = ov0;
    *(float2*)&pp[r][1][d2] = ov1;
    *(float2*)&pp[r][2][d2] = ov2;
    *(float2*)&pp[r][3][d2] = ov3;
    __syncthreads();                                   // D

    // ---- o combine: wave r sums partials for row r; publish to cop ----
    float2 o;
    {
        float2 q0 = *(const float2*)&pp[0][r][d2];
        float2 q1 = *(const float2*)&pp[1][r][d2];
        float2 q2 = *(const float2*)&pp[2][r][d2];
        float2 q3 = *(const float2*)&pp[3][r][d2];
        o.x = (q0.x + q1.x) + (q2.x + q3.x);
        o.y = (q0.y + q1.y) + (q2.y + q3.y);
    }
    *(float2*)&cop[r][DIMH + d2] = o;
    __syncthreads();                                   // E: gate reads o rows

    // ---- gate split-K: wave w owns W rows e in [64w, 64w+64), direct from global ----
    float cv0 = cop[0][64 * r + lane];                 // c[row][64w + lane]
    float cv1 = cop[1][64 * r + lane];
    float cv2 = cop[2][64 * r + lane];
    float cv3 = cop[3][64 * r + lane];
    float2 gv0 = {0.f,0.f}, gv1 = {0.f,0.f}, gv2 = {0.f,0.f}, gv3 = {0.f,0.f};
    {
        const float* wb = W + (size_t)(64 * r) * DIMH + d2;
        #pragma unroll 8
        for (int ee = 0; ee < 64; ++ee) {
            float2 wv = *(const float2*)(wb + ee * DIMH);
            float c0 = rdlane(cv0, ee), c1 = rdlane(cv1, ee);
            float c2 = rdlane(cv2, ee), c3 = rdlane(cv3, ee);
            gv0.x = fmaf(c0, wv.x, gv0.x); gv0.y = fmaf(c0, wv.y, gv0.y);
            gv1.x = fmaf(c1, wv.x, gv1.x); gv1.y = fmaf(c1, wv.y, gv1.y);
            gv2.x = fmaf(c2, wv.x, gv2.x); gv2.y = fmaf(c2, wv.y, gv2.y);
            gv3.x = fmaf(c3, wv.x, gv3.x); gv3.y = fmaf(c3, wv.y, gv3.y);
        }
    }
    *(float2*)&pp[r][0][d2] = gv0;                     // reuse pp for gate partials
    *(float2*)&pp[r][1][d2] = gv1;
    *(float2*)&pp[r][2][d2] = gv2;
    *(float2*)&pp[r][3][d2] = gv3;
    __syncthreads();                                   // F

    // ---- final: wave r combines gate partials for row r, mixes, stores ----
    {
        float2 q0 = *(const float2*)&pp[0][r][d2];
        float2 q1 = *(const float2*)&pp[1][r][d2];
        float2 q2 = *(const float2*)&pp[2][r][d2];
        float2 q3 = *(const float2*)&pp[3][r][d2];
        float2 bv = *(const float2*)(bias + d2);
        float gx = ((q0.x + q1.x) + (q2.x + q3.x)) + bv.x;
        float gy = ((q0.y + q1.y) + (q2.y + q3.y)) + bv.y;
        float sgx = 1.0f / (1.0f + __expf(-gx));
        float sgy = 1.0f / (1.0f + __expf(-gy));
        float2 hf = *(const float2*)&cop[r][d2];
        const size_t gi = (size_t)(b * NB + i0 + r) * DIMH;
        float2 res;
        res.x = sgx * o.x + (1.0f - sgx) * hf.x;
        res.y = sgy * o.y + (1.0f - sgy) * hf.y;
        *(float2*)(out + gi + d2) = res;
    }
}

extern "C" void kernel_launch(void* const* d_in, const int* in_sizes, int n_in,
                              void* d_out, int out_size, void* d_ws, size_t ws_size,
                              hipStream_t stream)
{
    const float* hidden = (const float*)d_in[0];
    const int*   adj    = (const int*)d_in[1];
    const int*   mask   = (const int*)d_in[2];
    const float* a0     = (const float*)d_in[3];
    const float* a1     = (const float*)d_in[4];
    const float* a2     = (const float*)d_in[5];
    const float* a3     = (const float*)d_in[6];
    const float* W      = (const float*)d_in[7];
    const float* bias   = (const float*)d_in[8];
    float* out = (float*)d_out;

    const int B = in_sizes[0] / (NB * DIMH);   // 256
    dim3 grid(B * (NB / ROWS));
    la_fused<<<grid, TPB, 0, stream>>>(hidden, adj, mask, a0, a1, a2, a3, W, bias, out);
}

// Round 10
// 335.651 us; speedup vs baseline: 1.2031x; 1.0750x over previous
//
#include <hip/hip_runtime.h>
#include <math.h>

#define NB    200
#define DIMH  128
#define ROWS  4
#define TPB   256
#define NITER 12   // tau err 0.411*2^-12 ~ 1e-4 -> p err ~1e-3, threshold 8.5e-2
#define NJT   13   // j-tiles of 16 covering 208

typedef __attribute__((ext_vector_type(8))) short  short8v;  // 8 bf16 (MFMA A/B frag)
typedef __attribute__((ext_vector_type(4))) float  f32x4;    // MFMA C/D frag
typedef __attribute__((ext_vector_type(4))) unsigned u32x4;

#define WF_U32 32768   // W-frag table: 8nt*8ks*64lane*4 u32 (hi) + same (lo)

// Truncation hi/lo split: hi = top-16-bits of f32 (exact), lo = x - hi (exact f32).
__device__ __forceinline__ unsigned pack_hi2(float a, float b){
    return (__builtin_bit_cast(unsigned, a) >> 16) |
           (__builtin_bit_cast(unsigned, b) & 0xFFFF0000u);
}
__device__ __forceinline__ float hi_of(float x){
    return __builtin_bit_cast(float, __builtin_bit_cast(unsigned, x) & 0xFFFF0000u);
}
__device__ __forceinline__ float rdlane(float v, int l){
    return __builtin_bit_cast(float,
        __builtin_amdgcn_readlane(__builtin_bit_cast(int, v), l));
}
__device__ __forceinline__ float wsum_dpp(float v){
#define DPP_ADD(ctrl, rmask)                                                     \
    {                                                                            \
        int t_ = __builtin_amdgcn_update_dpp(0, __builtin_bit_cast(int, v),      \
                                             ctrl, rmask, 0xf, false);           \
        v += __builtin_bit_cast(float, t_);                                      \
    }
    DPP_ADD(0x111, 0xf)
    DPP_ADD(0x112, 0xf)
    DPP_ADD(0x114, 0xf)
    DPP_ADD(0x118, 0xf)
    DPP_ADD(0x142, 0xa)
    DPP_ADD(0x143, 0xc)
#undef DPP_ADD
    return rdlane(v, 63);
}
__device__ __forceinline__ float wmax_dpp(float v){
#define DPP_MAX(ctrl, rmask)                                                     \
    {                                                                            \
        int t_ = __builtin_amdgcn_update_dpp(__builtin_bit_cast(int, v),         \
                                             __builtin_bit_cast(int, v),         \
                                             ctrl, rmask, 0xf, false);           \
        v = fmaxf(v, __builtin_bit_cast(float, t_));                             \
    }
    DPP_MAX(0x111, 0xf)
    DPP_MAX(0x112, 0xf)
    DPP_MAX(0x114, 0xf)
    DPP_MAX(0x118, 0xf)
    DPP_MAX(0x142, 0xa)
    DPP_MAX(0x143, 0xc)
#undef DPP_MAX
    return rdlane(v, 63);
}

// One-time W -> bf16 hi/lo fragment table (layout matches gate MFMA B-frag).
__global__ __launch_bounds__(64) void conv_w(const float* __restrict__ W,
                                             unsigned* __restrict__ wf){
    const int lane = threadIdx.x;
    const int ks = blockIdx.x & 7, nt = blockIdx.x >> 3;
    const int krow = ks * 32 + (lane >> 4) * 8;
    const int col  = nt * 16 + (lane & 15);
    unsigned hi[4], lo[4];
    #pragma unroll
    for (int q2 = 0; q2 < 4; ++q2) {
        float v0 = W[(size_t)(krow + 2 * q2) * DIMH + col];
        float v1 = W[(size_t)(krow + 2 * q2 + 1) * DIMH + col];
        hi[q2] = pack_hi2(v0, v1);
        lo[q2] = pack_hi2(v0 - hi_of(v0), v1 - hi_of(v1));
    }
    const unsigned base = (blockIdx.x * 64 + lane) * 4;
    *(u32x4*)&wf[base]          = (u32x4){hi[0], hi[1], hi[2], hi[3]};
    *(u32x4*)&wf[WF_U32 / 2 + base] = (u32x4){lo[0], lo[1], lo[2], lo[3]};
}

// (256,4): only empirically spill-free config. WRITE_SIZE tripwire: 25600KB.
template<bool GM>
__global__ __launch_bounds__(TPB, 4) void la_fused(
    const float* __restrict__ hidden,
    const int*   __restrict__ adj,
    const int*   __restrict__ mask,
    const float* __restrict__ a0, const float* __restrict__ a1,
    const float* __restrict__ a2, const float* __restrict__ a3,
    const float* __restrict__ W,  const float* __restrict__ bias,
    const unsigned* __restrict__ wf,
    float* __restrict__ out)
{
    __shared__ unsigned hab[2][16][68];    // ha bf16x2 [hi/lo][rk][d2]
    __shared__ float xs[ROWS][208];        // scores -> normalized p
    __shared__ float cop[ROWS][256];       // [0:128)=h_i, [128:256)=o (o only used if !GM)
    __shared__ float pp[ROWS][ROWS][DIMH]; // PV partials; reused as gbuf[4][128]
    __shared__ unsigned cbf[2][ROWS][132]; // gate A rows bf16x2 [hi/lo][row][u32], padded

    const int t    = threadIdx.x;
    const int lane = t & 63;
    const int r    = t >> 6;
    const int d2   = 2 * lane;
    const int bid  = blockIdx.x;
    const int b    = bid / (NB / ROWS);
    const int i0   = (bid % (NB / ROWS)) * ROWS;

    const float* hb = hidden + (size_t)b * NB * DIMH;

    // ---- stage h_i rows (cop) and the bf16 hi/lo ha table ----
    for (int idx = t; idx < ROWS * DIMH; idx += TPB) {
        int rr = idx >> 7, d = idx & 127;
        cop[rr][d] = hb[(i0 + rr) * DIMH + d];
    }
    for (int s = t; s < 16 * 64; s += TPB) {
        int rk = s >> 6, dd = s & 63;
        int rr = rk >> 2, k = rk & 3;
        int d  = dd * 2;
        const float* ap = (k == 0) ? a0 : (k == 1) ? a1 : (k == 2) ? a2 : a3;
        float h0 = hb[(i0 + rr) * DIMH + d];
        float h1 = hb[(i0 + rr) * DIMH + d + 1];
        float q0 = h0 * ap[d];
        float q1 = h1 * ap[d + 1];
        hab[0][rk][dd] = pack_hi2(q0, q1);
        hab[1][rk][dd] = pack_hi2(q0 - hi_of(q0), q1 - hi_of(q1));
    }
    __syncthreads();                                   // A

    // ---- A-fragments for score ----
    short8v Ahi[4], Alo[4];
    {
        const int arow = lane & 15;
        const int au   = (lane >> 4) * 4;
        #pragma unroll
        for (int ks = 0; ks < 4; ++ks) {
            Ahi[ks] = __builtin_bit_cast(short8v, *(const u32x4*)&hab[0][arow][ks * 16 + au]);
            Alo[ks] = __builtin_bit_cast(short8v, *(const u32x4*)&hab[1][arow][ks * 16 + au]);
        }
    }

    // ---- score via MFMA ----
    const int jcol = lane & 15;
    const int kgrp = lane >> 4;
    for (int jt = r; jt < NJT; jt += 4) {
        const int jrow = jt * 16 + jcol;
        const int jl   = (jrow < NB) ? jrow : (NB - 1);
        const float* hj = hb + (size_t)jl * DIMH + kgrp * 8;
        f32x4 acc = {0.f, 0.f, 0.f, 0.f};
        #pragma unroll
        for (int ks = 0; ks < 4; ++ks) {
            float4 ra = *(const float4*)(hj + ks * 32);
            float4 rb = *(const float4*)(hj + ks * 32 + 4);
            u32x4 bh = { pack_hi2(ra.x, ra.y), pack_hi2(ra.z, ra.w),
                         pack_hi2(rb.x, rb.y), pack_hi2(rb.z, rb.w) };
            u32x4 bl = { pack_hi2(ra.x - hi_of(ra.x), ra.y - hi_of(ra.y)),
                         pack_hi2(ra.z - hi_of(ra.z), ra.w - hi_of(ra.w)),
                         pack_hi2(rb.x - hi_of(rb.x), rb.y - hi_of(rb.y)),
                         pack_hi2(rb.z - hi_of(rb.z), rb.w - hi_of(rb.w)) };
            short8v Bhi = __builtin_bit_cast(short8v, bh);
            short8v Blo = __builtin_bit_cast(short8v, bl);
            acc = __builtin_amdgcn_mfma_f32_16x16x32_bf16(Ahi[ks], Bhi, acc, 0, 0, 0);
            acc = __builtin_amdgcn_mfma_f32_16x16x32_bf16(Alo[ks], Bhi, acc, 0, 0, 0);
            acc = __builtin_amdgcn_mfma_f32_16x16x32_bf16(Ahi[ks], Blo, acc, 0, 0, 0);
        }
        int kk = adj[(size_t)(b * NB + i0 + kgrp) * NB + jl];
        int mm = mask[b * NB + jl];
        float ev = (kk == 1) ? acc[0] : (kk == 2) ? acc[1] :
                   (kk == 3) ? acc[2] : (kk == 4) ? acc[3] : 0.0f;
        ev = (ev >= 0.0f) ? ev : 0.2f * ev;
        float x = ev * 0.1f;
        if (mm == 0)     x = -INFINITY;
        if (jrow >= NB)  x = -INFINITY;
        xs[kgrp][jrow] = x;
    }
    __syncthreads();                                   // B

    // ---- entmax bisection ----
    float x0 = xs[r][lane];
    float x1 = xs[r][lane + 64];
    float x2 = xs[r][lane + 128];
    float x3 = (lane < 16) ? xs[r][192 + lane] : -INFINITY;

    float mx  = wmax_dpp(fmaxf(fmaxf(x0, x1), fmaxf(x2, x3)));
    float tau = mx - 1.0f;
    #define P10(v, tt) ({ float z_ = fmaxf((v) - (tt), 0.f); float z2 = z_*z_; float z4 = z2*z2; float z8 = z4*z4; z8*z2; })
    float s0 = P10(x0, tau) + P10(x1, tau) + P10(x2, tau) + P10(x3, tau);
    float f_lo = wsum_dpp(s0) - 1.0f;
    float dm   = (mx - 0.58870401f) - tau;

    for (int itn = 0; itn < NITER; ++itn) {
        dm *= 0.5f;
        float tm = tau + dm;
        float s = P10(x0, tm) + P10(x1, tm) + P10(x2, tm) + P10(x3, tm);
        float fm = wsum_dpp(s) - 1.0f;
        if (fm * f_lo >= 0.0f) tau = tm;
    }
    float p0 = P10(x0, tau);
    float p1 = P10(x1, tau);
    float p2 = P10(x2, tau);
    float p3 = P10(x3, tau);
    #undef P10
    float sinv = 1.0f / wsum_dpp(p0 + p1 + p2 + p3);
    xs[r][lane]       = p0 * sinv;
    xs[r][lane + 64]  = p1 * sinv;
    xs[r][lane + 128] = p2 * sinv;
    if (lane < 16) xs[r][192 + lane] = p3 * sinv;
    __syncthreads();                                   // C

    // ---- PV split-K: wave w owns j in [50w, 50w+50) ----
    const int J0 = r * 50;
    float pj0 = (lane < 50) ? xs[0][J0 + lane] : 0.f;
    float pj1 = (lane < 50) ? xs[1][J0 + lane] : 0.f;
    float pj2 = (lane < 50) ? xs[2][J0 + lane] : 0.f;
    float pj3 = (lane < 50) ? xs[3][J0 + lane] : 0.f;
    float2 ov0 = {0.f,0.f}, ov1 = {0.f,0.f}, ov2 = {0.f,0.f}, ov3 = {0.f,0.f};
    {
        const float* hjb = hb + (size_t)J0 * DIMH + d2;
        #pragma unroll 5
        for (int jj = 0; jj < 50; ++jj) {
            float2 hv = *(const float2*)(hjb + jj * DIMH);
            float c0 = rdlane(pj0, jj), c1 = rdlane(pj1, jj);
            float c2 = rdlane(pj2, jj), c3 = rdlane(pj3, jj);
            ov0.x = fmaf(c0, hv.x, ov0.x); ov0.y = fmaf(c0, hv.y, ov0.y);
            ov1.x = fmaf(c1, hv.x, ov1.x); ov1.y = fmaf(c1, hv.y, ov1.y);
            ov2.x = fmaf(c2, hv.x, ov2.x); ov2.y = fmaf(c2, hv.y, ov2.y);
            ov3.x = fmaf(c3, hv.x, ov3.x); ov3.y = fmaf(c3, hv.y, ov3.y);
        }
    }
    *(float2*)&pp[r][0][d2] = ov0;
    *(float2*)&pp[r][1][d2] = ov1;
    *(float2*)&pp[r][2][d2] = ov2;
    *(float2*)&pp[r][3][d2] = ov3;
    __syncthreads();                                   // D

    // ---- o combine (wave r owns row r) ----
    float2 o;
    {
        float2 q0 = *(const float2*)&pp[0][r][d2];
        float2 q1 = *(const float2*)&pp[1][r][d2];
        float2 q2 = *(const float2*)&pp[2][r][d2];
        float2 q3 = *(const float2*)&pp[3][r][d2];
        o.x = (q0.x + q1.x) + (q2.x + q3.x);
        o.y = (q0.y + q1.y) + (q2.y + q3.y);
    }

    float2 gres;   // this wave's row-r gate pre-activation at dims d2, d2+1

    if constexpr (GM) {
        // pack c row r = [h_i | o] as bf16 hi/lo (k-pairs -> u32)
        float hx = cop[r][d2], hy = cop[r][d2 + 1];
        cbf[0][r][lane]      = pack_hi2(hx, hy);
        cbf[1][r][lane]      = pack_hi2(hx - hi_of(hx), hy - hi_of(hy));
        cbf[0][r][64 + lane] = pack_hi2(o.x, o.y);
        cbf[1][r][64 + lane] = pack_hi2(o.x - hi_of(o.x), o.y - hi_of(o.y));
        __syncthreads();                               // E

        // gate MFMA: wave r does n-tiles 2r, 2r+1; A rows duplicated via lane&3
        f32x4 ga0 = {0.f,0.f,0.f,0.f}, ga1 = {0.f,0.f,0.f,0.f};
        const int arow = lane & 3;
        const int au   = (lane >> 4) * 4;
        #pragma unroll
        for (int ks = 0; ks < 8; ++ks) {
            short8v Ah = __builtin_bit_cast(short8v, *(const u32x4*)&cbf[0][arow][ks * 16 + au]);
            short8v Al = __builtin_bit_cast(short8v, *(const u32x4*)&cbf[1][arow][ks * 16 + au]);
            const unsigned bi0 = (((2 * r) * 8 + ks) * 64 + lane) * 4;
            const unsigned bi1 = (((2 * r + 1) * 8 + ks) * 64 + lane) * 4;
            short8v Bh0 = __builtin_bit_cast(short8v, *(const u32x4*)&wf[bi0]);
            short8v Bl0 = __builtin_bit_cast(short8v, *(const u32x4*)&wf[WF_U32 / 2 + bi0]);
            short8v Bh1 = __builtin_bit_cast(short8v, *(const u32x4*)&wf[bi1]);
            short8v Bl1 = __builtin_bit_cast(short8v, *(const u32x4*)&wf[WF_U32 / 2 + bi1]);
            ga0 = __builtin_amdgcn_mfma_f32_16x16x32_bf16(Ah, Bh0, ga0, 0, 0, 0);
            ga0 = __builtin_amdgcn_mfma_f32_16x16x32_bf16(Al, Bh0, ga0, 0, 0, 0);
            ga0 = __builtin_amdgcn_mfma_f32_16x16x32_bf16(Ah, Bl0, ga0, 0, 0, 0);
            ga1 = __builtin_amdgcn_mfma_f32_16x16x32_bf16(Ah, Bh1, ga1, 0, 0, 0);
            ga1 = __builtin_amdgcn_mfma_f32_16x16x32_bf16(Al, Bh1, ga1, 0, 0, 0);
            ga1 = __builtin_amdgcn_mfma_f32_16x16x32_bf16(Ah, Bl1, ga1, 0, 0, 0);
        }
        // D rows 0-3 live in lanes 0-15, regs 0-3; col = nt*16 + (lane&15)
        float* gbuf = &pp[0][0][0];                    // reuse pp as gbuf[4][128]
        if (lane < 16) {
            #pragma unroll
            for (int m = 0; m < 4; ++m) {
                gbuf[m * DIMH + (2 * r) * 16 + lane]     = ga0[m];
                gbuf[m * DIMH + (2 * r + 1) * 16 + lane] = ga1[m];
            }
        }
        __syncthreads();                               // F
        gres.x = gbuf[r * DIMH + d2];
        gres.y = gbuf[r * DIMH + d2 + 1];
    } else {
        // fallback: f32 split-K gate (round-9 path)
        *(float2*)&cop[r][DIMH + d2] = o;
        __syncthreads();                               // E
        float cv0 = cop[0][64 * r + lane];
        float cv1 = cop[1][64 * r + lane];
        float cv2 = cop[2][64 * r + lane];
        float cv3 = cop[3][64 * r + lane];
        float2 gv0 = {0.f,0.f}, gv1 = {0.f,0.f}, gv2 = {0.f,0.f}, gv3 = {0.f,0.f};
        const float* wb = W + (size_t)(64 * r) * DIMH + d2;
        #pragma unroll 8
        for (int ee = 0; ee < 64; ++ee) {
            float2 wv = *(const float2*)(wb + ee * DIMH);
            float c0 = rdlane(cv0, ee), c1 = rdlane(cv1, ee);
            float c2 = rdlane(cv2, ee), c3 = rdlane(cv3, ee);
            gv0.x = fmaf(c0, wv.x, gv0.x); gv0.y = fmaf(c0, wv.y, gv0.y);
            gv1.x = fmaf(c1, wv.x, gv1.x); gv1.y = fmaf(c1, wv.y, gv1.y);
            gv2.x = fmaf(c2, wv.x, gv2.x); gv2.y = fmaf(c2, wv.y, gv2.y);
            gv3.x = fmaf(c3, wv.x, gv3.x); gv3.y = fmaf(c3, wv.y, gv3.y);
        }
        *(float2*)&pp[r][0][d2] = gv0;
        *(float2*)&pp[r][1][d2] = gv1;
        *(float2*)&pp[r][2][d2] = gv2;
        *(float2*)&pp[r][3][d2] = gv3;
        __syncthreads();                               // F
        float2 q0 = *(const float2*)&pp[0][r][d2];
        float2 q1 = *(const float2*)&pp[1][r][d2];
        float2 q2 = *(const float2*)&pp[2][r][d2];
        float2 q3 = *(const float2*)&pp[3][r][d2];
        gres.x = (q0.x + q1.x) + (q2.x + q3.x);
        gres.y = (q0.y + q1.y) + (q2.y + q3.y);
    }

    // ---- final: bias, sigmoid, mix, store ----
    {
        float2 bv = *(const float2*)(bias + d2);
        float gx = gres.x + bv.x;
        float gy = gres.y + bv.y;
        float sgx = 1.0f / (1.0f + __expf(-gx));
        float sgy = 1.0f / (1.0f + __expf(-gy));
        float2 hf = *(const float2*)&cop[r][d2];
        const size_t gi = (size_t)(b * NB + i0 + r) * DIMH;
        float2 res;
        res.x = sgx * o.x + (1.0f - sgx) * hf.x;
        res.y = sgy * o.y + (1.0f - sgy) * hf.y;
        *(float2*)(out + gi + d2) = res;
    }
}

extern "C" void kernel_launch(void* const* d_in, const int* in_sizes, int n_in,
                              void* d_out, int out_size, void* d_ws, size_t ws_size,
                              hipStream_t stream)
{
    const float* hidden = (const float*)d_in[0];
    const int*   adj    = (const int*)d_in[1];
    const int*   mask   = (const int*)d_in[2];
    const float* a0     = (const float*)d_in[3];
    const float* a1     = (const float*)d_in[4];
    const float* a2     = (const float*)d_in[5];
    const float* a3     = (const float*)d_in[6];
    const float* W      = (const float*)d_in[7];
    const float* bias   = (const float*)d_in[8];
    float* out = (float*)d_out;

    const int B = in_sizes[0] / (NB * DIMH);   // 256
    dim3 grid(B * (NB / ROWS));

    if (ws_size >= WF_U32 * sizeof(unsigned)) {
        unsigned* wf = (unsigned*)d_ws;
        conv_w<<<64, 64, 0, stream>>>(W, wf);
        la_fused<true><<<grid, TPB, 0, stream>>>(hidden, adj, mask, a0, a1, a2, a3,
                                                 W, bias, wf, out);
    } else {
        la_fused<false><<<grid, TPB, 0, stream>>>(hidden, adj, mask, a0, a1, a2, a3,
                                                  W, bias, (const unsigned*)nullptr, out);
    }
}